// Round 1
// baseline (247.238 us; speedup 1.0000x reference)
//
#include <hip/hip_runtime.h>

// out[b,i,j,f] = x[b,i,f] * y[b,j,f]; outputs: (out, 0.75*out) concatenated.
// B=100000, 3x3 outer over i/j, F=128. Pure streaming, zero reuse ->
// nontemporal loads/stores, stores grouped per output stream.
// Thread t: b = t>>5, fv = t&31 (32 float4 per 128 floats).

typedef float v4 __attribute__((ext_vector_type(4)));

#define FV 32  // 128 floats / 4 per float4

__global__ __launch_bounds__(256) void tp_outer_kernel(
    const v4* __restrict__ x,
    const v4* __restrict__ y,
    v4* __restrict__ out0,
    v4* __restrict__ out1,
    int total)  // total = B * FV threads of work
{
    int tid = blockIdx.x * blockDim.x + threadIdx.x;
    if (tid >= total) return;

    int b  = tid >> 5;
    int fv = tid & 31;

    // x[b][i][*]: float4 index (b*3 + i)*FV + fv. Read-once -> nontemporal.
    size_t ibase = (size_t)(b * 3) * FV + fv;
    v4 xs[3], ys[3];
#pragma unroll
    for (int i = 0; i < 3; ++i) {
        xs[i] = __builtin_nontemporal_load(&x[ibase + (size_t)i * FV]);
        ys[i] = __builtin_nontemporal_load(&y[ibase + (size_t)i * FV]);
    }

    // All 9 products in registers (9 x float4 = 36 VGPRs payload).
    v4 o[9];
#pragma unroll
    for (int i = 0; i < 3; ++i)
#pragma unroll
        for (int j = 0; j < 3; ++j)
            o[i * 3 + j] = xs[i] * ys[j];

    size_t obase = (size_t)b * 9 * FV + fv;

    // Grouped nontemporal stores: one stream at a time, no L2 retention.
#pragma unroll
    for (int k = 0; k < 9; ++k)
        __builtin_nontemporal_store(o[k], &out0[obase + (size_t)k * FV]);
#pragma unroll
    for (int k = 0; k < 9; ++k)
        __builtin_nontemporal_store(o[k] * 0.75f, &out1[obase + (size_t)k * FV]);
}

extern "C" void kernel_launch(void* const* d_in, const int* in_sizes, int n_in,
                              void* d_out, int out_size, void* d_ws, size_t ws_size,
                              hipStream_t stream) {
    const v4* x = (const v4*)d_in[0];
    const v4* y = (const v4*)d_in[1];

    // in_sizes[0] = B*3*128 floats
    int B = in_sizes[0] / (3 * 128);
    int total = B * FV;  // B * 32 float4-groups

    // out_size = 2 * B*9*128 floats; second output starts at half.
    float* out_f = (float*)d_out;
    v4* out0 = (v4*)out_f;
    v4* out1 = (v4*)(out_f + (size_t)out_size / 2);

    int block = 256;
    int grid = (total + block - 1) / block;
    tp_outer_kernel<<<grid, block, 0, stream>>>(x, y, out0, out1, total);
}

// Round 2
// 242.458 us; speedup vs baseline: 1.0197x; 1.0197x over previous
//
#include <hip/hip_runtime.h>

// out[b,i,j,f] = x[b,i,f] * y[b,j,f]; outputs: (out, 0.75*out) concatenated.
// B=100000, 3x3 outer over i/j, F=128. Memory-bound 1R:3W stream.
// This round: batch BPT=4 b's per thread -> 24 back-to-back dwordx4 loads
// per thread (4x read burst) before the store phase, to reduce HBM
// read/write turnaround mixing. Plain loads/stores (nt was neutral in R1).

typedef float v4 __attribute__((ext_vector_type(4)));

#define FV 32   // 128 floats / 4 per float4
#define BPT 4   // b values per thread (100000 % 4 == 0)

__global__ __launch_bounds__(256) void tp_outer_kernel(
    const v4* __restrict__ x,
    const v4* __restrict__ y,
    v4* __restrict__ out0,
    v4* __restrict__ out1,
    int total)  // total = (B/BPT) * FV threads
{
    int tid = blockIdx.x * blockDim.x + threadIdx.x;
    if (tid >= total) return;

    int bq = tid >> 5;        // which 4-b group
    int fv = tid & 31;        // float4 lane within 128-float feature row
    int b0 = bq * BPT;

    // ---- read phase: 24 loads issued back-to-back ----
    v4 xs[BPT][3], ys[BPT][3];
    size_t ibase = (size_t)b0 * 3 * FV + fv;
#pragma unroll
    for (int u = 0; u < BPT; ++u)
#pragma unroll
        for (int i = 0; i < 3; ++i)
            xs[u][i] = x[ibase + (size_t)(u * 3 + i) * FV];
#pragma unroll
    for (int u = 0; u < BPT; ++u)
#pragma unroll
        for (int i = 0; i < 3; ++i)
            ys[u][i] = y[ibase + (size_t)(u * 3 + i) * FV];

    // ---- compute + store phase: 72 stores ----
    size_t obase = (size_t)b0 * 9 * FV + fv;
#pragma unroll
    for (int u = 0; u < BPT; ++u) {
#pragma unroll
        for (int i = 0; i < 3; ++i) {
#pragma unroll
            for (int j = 0; j < 3; ++j) {
                v4 o = xs[u][i] * ys[u][j];
                size_t oidx = obase + (size_t)(u * 9 + i * 3 + j) * FV;
                out0[oidx] = o;
                out1[oidx] = o * 0.75f;
            }
        }
    }
}

extern "C" void kernel_launch(void* const* d_in, const int* in_sizes, int n_in,
                              void* d_out, int out_size, void* d_ws, size_t ws_size,
                              hipStream_t stream) {
    const v4* x = (const v4*)d_in[0];
    const v4* y = (const v4*)d_in[1];

    // in_sizes[0] = B*3*128 floats
    int B = in_sizes[0] / (3 * 128);
    int total = (B / BPT) * FV;

    // out_size = 2 * B*9*128 floats; second output starts at half.
    float* out_f = (float*)d_out;
    v4* out0 = (v4*)out_f;
    v4* out1 = (v4*)(out_f + (size_t)out_size / 2);

    int block = 256;
    int grid = (total + block - 1) / block;
    tp_outer_kernel<<<grid, block, 0, stream>>>(x, y, out0, out1, total);
}